// Round 25
// baseline (274.907 us; speedup 1.0000x reference)
//
#include <hip/hip_runtime.h>
#include <hip/hip_bf16.h>

#define S_LEN 2048
#define HID   2048
#define NH    16
#define NKV   4
#define HD    128
#define KVD   512            // NKV*HD
#define NQKV  3072           // HID + KVD + KVD
#define SCALE2 0.0078125f    // (D^-0.5)^2 = 1/128
#define NCH   80             // j-chunk slots per head: sum_{qt} ceil((qt+1)/8)

typedef __bf16 bf16;
typedef __attribute__((ext_vector_type(8))) __bf16 bf16x8;
typedef __attribute__((ext_vector_type(4))) __bf16 bf16x4;
typedef __attribute__((ext_vector_type(4))) float f32x4;

// async global->LDS, 16B per lane; LDS dest is wave-uniform base + lane*16
__device__ __forceinline__ void gload_lds16(const bf16* g, bf16* l) {
    __builtin_amdgcn_global_load_lds((const __attribute__((address_space(1))) void*)g,
                                     (__attribute__((address_space(3))) void*)l, 16, 0, 0);
}

// ---------------------------------------------------------------------------
// Within-64B both-sides XOR swizzle (rule #21):
//   LDS rows are 64 B = four 16 B slots. Physical slot sp of row r holds
//   logical slot sp ^ ((r>>1)&3). Staged via linear gload_lds dest +
//   permuted GLOBAL source col ((lane&3)^((lane>>3)&3))*8 (stays inside the
//   same 64-B run per 4-lane group => FETCH unchanged). Reads XOR the slot
//   with ((l16>>1)&3). Turns the 8-way b128 fragment-read conflict into
//   2-way (= free, m136). Round-11 verified: qkv conflicts 3.15M -> 0,
//   FETCH flat, refcheck pass.
// ---------------------------------------------------------------------------

// ---------------------------------------------------------------------------
// Fused pre-pass. Region-decoded grid:
//   [0,2048)    : hs f32 -> hsb bf16  + FUSED gate projection (row b)
//   [2048,3072) : Wq transpose-cvt -> WcatT[0]
//   [3072,3328) : Wk -> WcatT[2048*HID]
//   [3328,3584) : Wv -> WcatT[2560*HID]
//   [3584,4608) : Wo -> WoT
//   [4608,6656) : zero d_out (for wo atomics)
// ---------------------------------------------------------------------------
__device__ __forceinline__ void transpose_tile(const float* __restrict__ W,
                                               bf16* __restrict__ Wt,
                                               int K, int N, int bx, int by,
                                               int t, float (*Ts)[65])
{
    const int kb = bx * 64, nb = by * 64;
    const int tr = t >> 6, tc = t & 63;
    #pragma unroll
    for (int p = 0; p < 16; ++p) {
        int k = p * 4 + tr;
        Ts[k][tc] = W[(size_t)(kb + k) * N + nb + tc];
    }
    __syncthreads();
    const int nr = t >> 3, kc = t & 7;
    #pragma unroll
    for (int p = 0; p < 2; ++p) {
        int n = p * 32 + nr;
        bf16x8 o;
        #pragma unroll
        for (int x = 0; x < 8; ++x) o[x] = (bf16)Ts[kc * 8 + x][n];
        *(bf16x8*)&Wt[(size_t)(nb + n) * K + kb + kc * 8] = o;
    }
}

__global__ __launch_bounds__(256) void prep_kernel(const float* __restrict__ hs,
                                                   const float* __restrict__ Wq,
                                                   const float* __restrict__ Wk,
                                                   const float* __restrict__ Wv,
                                                   const float* __restrict__ Wo,
                                                   const float* __restrict__ Wg,
                                                   bf16* __restrict__ hsb,
                                                   bf16* __restrict__ WcatT,
                                                   bf16* __restrict__ WoT,
                                                   float* __restrict__ graw,
                                                   float* __restrict__ outz)
{
    __shared__ float Ts[64][65];
    __shared__ float red[4][4];
    const int b = blockIdx.x, tid = threadIdx.x;

    if (b < 2048) {                                   // cvt hs -> hsb + gproj
        int i = (b * 256 + tid) * 8;
        const float4* qp = (const float4*)&hs[i];
        float4 a = qp[0], c = qp[1];
        bf16x8 r;
        r[0]=(bf16)a.x; r[1]=(bf16)a.y; r[2]=(bf16)a.z; r[3]=(bf16)a.w;
        r[4]=(bf16)c.x; r[5]=(bf16)c.y; r[6]=(bf16)c.z; r[7]=(bf16)c.w;
        *(bf16x8*)&hsb[i] = r;

        const float4* wgp = (const float4*)&Wg[tid * 32];   // 8 float4 rows
        float h[8] = {a.x, a.y, a.z, a.w, c.x, c.y, c.z, c.w};
        float a0 = 0.f, a1 = 0.f, a2 = 0.f, a3 = 0.f;
        #pragma unroll
        for (int x = 0; x < 8; ++x) {
            float4 w = wgp[x];
            a0 += h[x] * w.x; a1 += h[x] * w.y;
            a2 += h[x] * w.z; a3 += h[x] * w.w;
        }
        #pragma unroll
        for (int off = 32; off >= 1; off >>= 1) {
            a0 += __shfl_xor(a0, off); a1 += __shfl_xor(a1, off);
            a2 += __shfl_xor(a2, off); a3 += __shfl_xor(a3, off);
        }
        const int w4 = tid >> 6;
        if ((tid & 63) == 0) {
            red[w4][0] = a0; red[w4][1] = a1; red[w4][2] = a2; red[w4][3] = a3;
        }
        __syncthreads();
        if (tid == 0) {
            #pragma unroll
            for (int cc = 0; cc < 4; ++cc) {
                float x = red[0][cc] + red[1][cc] + red[2][cc] + red[3][cc];
                graw[cc * S_LEN + b] = fminf(x, 0.f) - log1pf(expf(-fabsf(x)));
            }
        }
    } else if (b < 3072) {
        int lb = b - 2048;
        transpose_tile(Wq, WcatT, HID, HID, lb >> 5, lb & 31, tid, Ts);
    } else if (b < 3328) {
        int lb = b - 3072;
        transpose_tile(Wk, WcatT + (size_t)2048 * HID, HID, KVD, lb >> 3, lb & 7, tid, Ts);
    } else if (b < 3584) {
        int lb = b - 3328;
        transpose_tile(Wv, WcatT + (size_t)2560 * HID, HID, KVD, lb >> 3, lb & 7, tid, Ts);
    } else if (b < 4608) {
        int lb = b - 3584;
        transpose_tile(Wo, WoT, HID, HID, lb >> 5, lb & 31, tid, Ts);
    } else {                                          // zero d_out
        int i = ((b - 4608) * 256 + tid) * 8;
        float4 z = make_float4(0.f, 0.f, 0.f, 0.f);
        *(float4*)&outz[i] = z;
        *(float4*)&outz[i + 4] = z;
    }
}

// ---------------------------------------------------------------------------
// m97-style GEMM core loop: 128x128 tile, BK=32, 4 waves, 4x4 MFMA grid.
// Within-64B both-sides XOR swizzle applied (8-way -> 2-way on frag reads).
// Used by gemm_qkv. (BK=64 falsified twice for this shape: r4 & r12.)
// ---------------------------------------------------------------------------
__device__ __forceinline__ void gemm128_core(const bf16* __restrict__ A,
                                             const bf16* __restrict__ Bt,
                                             int K, int k0, int k1, int mb, int nb,
                                             bf16 (*As)[32], bf16 (*Bs)[32],
                                             f32x4 (*acc)[4],
                                             int w, int l16, int quad, int lane)
{
    const int m0 = (w & 1) * 64, n0 = (w >> 1) * 64;
    const int srow = lane >> 2;
    const int scol = ((lane & 3) ^ ((lane >> 3) & 3)) * 8;   // pre-swizzled src
    const int rsl  = (quad ^ ((l16 >> 1) & 3)) * 8;          // swizzled read slot

    for (int kt = k0; kt < k1; kt += 32) {
        __syncthreads();
        gload_lds16(&A [(size_t)(mb + w * 32 +      srow) * K + kt + scol], &As[w * 32     ][0]);
        gload_lds16(&A [(size_t)(mb + w * 32 + 16 + srow) * K + kt + scol], &As[w * 32 + 16][0]);
        gload_lds16(&Bt[(size_t)(nb + w * 32 +      srow) * K + kt + scol], &Bs[w * 32     ][0]);
        gload_lds16(&Bt[(size_t)(nb + w * 32 + 16 + srow) * K + kt + scol], &Bs[w * 32 + 16][0]);
        __syncthreads();

        bf16x8 af[4], bfr[4];
        #pragma unroll
        for (int t = 0; t < 4; ++t) af[t]  = *(const bf16x8*)&As[m0 + t * 16 + l16][rsl];
        #pragma unroll
        for (int u = 0; u < 4; ++u) bfr[u] = *(const bf16x8*)&Bs[n0 + u * 16 + l16][rsl];
        #pragma unroll
        for (int t = 0; t < 4; ++t)
            #pragma unroll
            for (int u = 0; u < 4; ++u)
                acc[t][u] = __builtin_amdgcn_mfma_f32_16x16x32_bf16(af[t], bfr[u], acc[t][u], 0, 0, 0);
    }
}

// ---------------------------------------------------------------------------
// 128x128 GEMM core, BK=64, single 32 KB LDS buffer, both-sides XOR swizzle
// (round-4-verified correct; proven faster for the wo shape).
// ---------------------------------------------------------------------------
__device__ __forceinline__ void gemm128_bk64(const bf16* __restrict__ A,
                                             const bf16* __restrict__ Bt,
                                             int K, int k0, int k1, int mb, int nb,
                                             bf16 (*As)[64], bf16 (*Bs)[64],
                                             f32x4 (*acc)[4],
                                             int w, int l16, int quad, int lane)
{
    const int m0 = (w & 1) * 64, n0 = (w >> 1) * 64;
    const int srow8 = lane >> 3;                    // 0..7
    const int scol8 = ((lane & 7) ^ srow8) * 8;     // pre-swizzled col (elems)
    const bf16* aP[4]; const bf16* bP[4];
    #pragma unroll
    for (int i = 0; i < 4; ++i) {
        aP[i] = &A [(size_t)(mb + w * 32 + i * 8 + srow8) * K + k0 + scol8];
        bP[i] = &Bt[(size_t)(nb + w * 32 + i * 8 + srow8) * K + k0 + scol8];
    }
    const int rsw = (l16 & 7) << 3;                 // read-side XOR (elems)

    const int nk = k1 - k0;
    for (int kt = 0; kt < nk; kt += 64) {
        __syncthreads();                            // prev-tile reads done
        #pragma unroll
        for (int i = 0; i < 4; ++i) {
            gload_lds16(aP[i] + kt, &As[w * 32 + i * 8][0]);
            gload_lds16(bP[i] + kt, &Bs[w * 32 + i * 8][0]);
        }
        __syncthreads();                            // loads landed (vmcnt drain)

        #pragma unroll
        for (int kk = 0; kk < 2; ++kk) {
            bf16x8 af[4], bfr[4];
            #pragma unroll
            for (int t = 0; t < 4; ++t)
                af[t]  = *(const bf16x8*)&As[m0 + t * 16 + l16][(kk * 32 + quad * 8) ^ rsw];
            #pragma unroll
            for (int u = 0; u < 4; ++u)
                bfr[u] = *(const bf16x8*)&Bs[n0 + u * 16 + l16][(kk * 32 + quad * 8) ^ rsw];
            #pragma unroll
            for (int t = 0; t < 4; ++t)
                #pragma unroll
                for (int u = 0; u < 4; ++u)
                    acc[t][u] = __builtin_amdgcn_mfma_f32_16x16x32_bf16(af[t], bfr[u], acc[t][u], 0, 0, 0);
        }
    }
}

// Fused QKV projection, split-K=2, PLAIN f32 stores into per-z slice buffers.
// Grid: (384, 1, 2) flat; XCD-bijective swizzle (384 % 8 == 0).
__global__ __launch_bounds__(256) void gemm_qkv_kernel(const bf16* __restrict__ A,
                                                       const bf16* __restrict__ Wt,
                                                       float* __restrict__ qsl,   // [2][S*HID]
                                                       float* __restrict__ ksl,   // [2][S*KVD]
                                                       float* __restrict__ vsl,   // [2][KVD*S]
                                                       int M, int K)
{
    __shared__ __attribute__((aligned(16))) bf16 As[128][32];
    __shared__ __attribute__((aligned(16))) bf16 Bs[128][32];
    const int tid = threadIdx.x, w = tid >> 6, lane = tid & 63;
    const int l16 = lane & 15, quad = lane >> 4;

    const int bid = blockIdx.x;                  // 0..383
    const int lin = (bid & 7) * 48 + (bid >> 3); // XCD chunking (bijective)
    const int mb = (lin / 24) * 128, nb = (lin % 24) * 128;

    const int m0 = (w & 1) * 64, n0 = (w >> 1) * 64;
    const int z = blockIdx.z, kh = K >> 1, k0 = z * kh;

    float* qd = qsl + (size_t)z * S_LEN * HID;
    float* kd = ksl + (size_t)z * S_LEN * KVD;
    float* vd = vsl + (size_t)z * S_LEN * KVD;

    f32x4 acc[4][4] = {};
    gemm128_core(A, Wt, K, k0, k0 + kh, mb, nb, As, Bs, acc, w, l16, quad, lane);

    #pragma unroll
    for (int t = 0; t < 4; ++t)
        #pragma unroll
        for (int u = 0; u < 4; ++u)
            #pragma unroll
            for (int r = 0; r < 4; ++r) {
                int row = mb + m0 + t * 16 + quad * 4 + r;
                int col = nb + n0 + u * 16 + l16;
                float val = acc[t][u][r];
                if (nb < 2048)       qd[(size_t)row * HID + col] = val;
                else if (nb < 2560)  kd[(size_t)row * KVD + (col - 2048)] = val;
                else                 vd[(size_t)(col - 2560) * S_LEN + row] = val;
            }
}

// Wo GEMM, split-K=2, atomic f32 accumulate into pre-zeroed out.
// BK=64 swizzled core. Grid: (256, 1, 2) flat; XCD-bijective swizzle.
__global__ __launch_bounds__(256) void gemm_wo_kernel(const bf16* __restrict__ A,
                                                      const bf16* __restrict__ Bt,
                                                      float* __restrict__ C,
                                                      int M, int N, int K)
{
    __shared__ __attribute__((aligned(16))) bf16 As[128][64];
    __shared__ __attribute__((aligned(16))) bf16 Bs[128][64];
    const int tid = threadIdx.x, w = tid >> 6, lane = tid & 63;
    const int l16 = lane & 15, quad = lane >> 4;

    const int bid = blockIdx.x;                  // 0..255
    const int lin = (bid & 7) * 32 + (bid >> 3); // XCD chunking (bijective)
    const int mb = (lin >> 4) * 128, nb = (lin & 15) * 128;

    const int m0 = (w & 1) * 64, n0 = (w >> 1) * 64;
    const int kh = K >> 1, k0 = blockIdx.z * kh;

    f32x4 acc[4][4] = {};
    gemm128_bk64(A, Bt, K, k0, k0 + kh, mb, nb, As, Bs, acc, w, l16, quad, lane);

    #pragma unroll
    for (int t = 0; t < 4; ++t)
        #pragma unroll
        for (int u = 0; u < 4; ++u)
            #pragma unroll
            for (int r = 0; r < 4; ++r) {
                int row = mb + m0 + t * 16 + quad * 4 + r;
                int col = nb + n0 + u * 16 + l16;
                unsafeAtomicAdd(&C[(size_t)row * N + col], acc[t][u][r]);
            }
}

// ---------------------------------------------------------------------------
// Merged RoPE, VECTORIZED (round-3 proven).
// ---------------------------------------------------------------------------
#define RQB2 2048   // S*NH*64 pairs / 4 per thread / 256
#define RKB2 512    // S*NKV*64 pairs / 4 per thread / 256
#define RVB  512    // S*KVD / 8 / 256
__global__ __launch_bounds__(256) void rope_kernel(const float* __restrict__ qsl,
                                                   const float* __restrict__ ksl,
                                                   const float* __restrict__ vsl,
                                                   bf16* __restrict__ qb,
                                                   bf16* __restrict__ kb,
                                                   bf16* __restrict__ vT,
                                                   const float* __restrict__ cosb,
                                                   const float* __restrict__ sinb,
                                                   const float* __restrict__ graw,
                                                   float* __restrict__ G)
{
    const int blk = blockIdx.x;
    if (blk < RQB2 + RKB2) {
        int idx;
        const float* src; size_t ssz; bf16* dst; int s, rem, stride;
        if (blk < RQB2) {
            idx = (blk * 256 + threadIdx.x) * 4;           // pair index
            src = qsl; ssz = (size_t)S_LEN * HID; dst = qb; stride = HID;
            s = idx / (NH * 64); rem = idx % (NH * 64);
        } else {
            idx = ((blk - RQB2) * 256 + threadIdx.x) * 4;
            src = ksl; ssz = (size_t)S_LEN * KVD; dst = kb; stride = KVD;
            s = idx / (NKV * 64); rem = idx % (NKV * 64);
        }
        int h = rem >> 6, d = rem & 63;                    // d multiple of 4
        size_t base = (size_t)s * stride + h * 128 + d;
        float4 lo0 = *(const float4*)&src[base];
        float4 lo1 = *(const float4*)&src[ssz + base];
        float4 hi0 = *(const float4*)&src[base + 64];
        float4 hi1 = *(const float4*)&src[ssz + base + 64];
        float4 cl  = *(const float4*)&cosb[s * 128 + d];
        float4 ch  = *(const float4*)&cosb[s * 128 + d + 64];
        float4 sl  = *(const float4*)&sinb[s * 128 + d];
        float4 sh  = *(const float4*)&sinb[s * 128 + d + 64];
        float x0[4] = {lo0.x + lo1.x, lo0.y + lo1.y, lo0.z + lo1.z, lo0.w + lo1.w};
        float x1[4] = {hi0.x + hi1.x, hi0.y + hi1.y, hi0.z + hi1.z, hi0.w + hi1.w};
        float clo[4] = {cl.x, cl.y, cl.z, cl.w}, chi[4] = {ch.x, ch.y, ch.z, ch.w};
        float slo[4] = {sl.x, sl.y, sl.z, sl.w}, shi[4] = {sh.x, sh.y, sh.z, sh.w};
        bf16x4 olo, ohi;
        #pragma unroll
        for (int x = 0; x < 4; ++x) {
            olo[x] = (bf16)(x0[x] * clo[x] - x1[x] * slo[x]);
            ohi[x] = (bf16)(x1[x] * chi[x] + x0[x] * shi[x]);
        }
        *(bf16x4*)&dst[base]      = olo;
        *(bf16x4*)&dst[base + 64] = ohi;
    } else if (blk < RQB2 + RKB2 + RVB) {
        int i = ((blk - RQB2 - RKB2) * 256 + threadIdx.x) * 8;
        const size_t ssz = (size_t)S_LEN * KVD;
        float4 u0 = *(const float4*)&vsl[i],       u1 = *(const float4*)&vsl[i + 4];
        float4 v0 = *(const float4*)&vsl[ssz + i], v1 = *(const float4*)&vsl[ssz + i + 4];
        bf16x8 r;
        r[0] = (bf16)(u0.x + v0.x); r[1] = (bf16)(u0.y + v0.y);
        r[2] = (bf16)(u0.z + v0.z); r[3] = (bf16)(u0.w + v0.w);
        r[4] = (bf16)(u1.x + v1.x); r[5] = (bf16)(u1.y + v1.y);
        r[6] = (bf16)(u1.z + v1.z); r[7] = (bf16)(u1.w + v1.w);
        *(bf16x8*)&vT[i] = r;
    } else {                               // cumsum, one block per kv head
        const int c = blk - (RQB2 + RKB2 + RVB);
        const int t = threadIdx.x;
        __shared__ float sums[256];
        float loc[8];
        float run = 0.f;
        #pragma unroll
        for (int i = 0; i < 8; ++i) { run += graw[c * S_LEN + t * 8 + i]; loc[i] = run; }
        sums[t] = run;
        __syncthreads();
        for (int off = 1; off < 256; off <<= 1) {
            float add = (t >= off) ? sums[t - off] : 0.f;
            __syncthreads();
            sums[t] += add;
            __syncthreads();
        }
        float offset = sums[t] - run;
        #pragma unroll
        for (int i = 0; i < 8; ++i) G[c * S_LEN + t * 8 + i] = offset + loc[i];
    }
}

// ---------------------------------------------------------------------------
// Causal decay attention, j-split, LDS-staged QBLK=64 (round-11 state:
// within-64B both-sides XOR swizzle on K/V staging + fragment reads).
// Block index REVERSED so the longest chunks (8 j-tiles, large qt) dispatch
// first and short blocks backfill the tail (load-balance; work-neutral).
// ---------------------------------------------------------------------------
__global__ __launch_bounds__(256) void attn_kernel(const bf16* __restrict__ q,
                                                   const bf16* __restrict__ k,
                                                   const bf16* __restrict__ vT,
                                                   const float* __restrict__ G,
                                                   bf16* __restrict__ out,
                                                   float* __restrict__ pO,
                                                   float* __restrict__ pden)
{
    int rem = (NCH - 1) - blockIdx.x, qt = 0, cch = 0;   // reversed: long first
    #pragma unroll
    for (int g = 0; g < 4; ++g) {
        int sz = 8 * (g + 1);
        if (rem < sz) { qt = g * 8 + rem / (g + 1); cch = rem % (g + 1); break; }
        rem -= sz;
    }
    const int gg = qt >> 3, nc = gg + 1;
    const int jt0 = cch * 8, jt1 = min(qt + 1, jt0 + 8);

    const int h = blockIdx.y, kvh = h >> 2;
    const int qb = qt * 64;
    const int tid = threadIdx.x, w = tid >> 6, lane = tid & 63;
    const int l16 = lane & 15, quad = lane >> 4;

    __shared__ __attribute__((aligned(16))) bf16 Ks4[4][64][32];
    __shared__ __attribute__((aligned(16))) bf16 Vt4[2][128][32];
    __shared__ __attribute__((aligned(16))) bf16 Sb[4][16][68];

    bf16x8 qf[4];
    const int qrow = qb + w * 16 + l16;
    #pragma unroll
    for (int kc = 0; kc < 4; ++kc)
        qf[kc] = *(const bf16x8*)&q[(size_t)qrow * HID + h * HD + kc * 32 + quad * 8];

    const int irow = qb + w * 16 + quad * 4;
    float Gq[4];
    #pragma unroll
    for (int r = 0; r < 4; ++r) Gq[r] = G[kvh * S_LEN + irow + r];

    const int sr4 = lane >> 2;
    const int sc4 = ((lane & 3) ^ ((lane >> 3) & 3)) * 8;   // pre-swizzled src
    const int rsl = (quad ^ ((l16 >> 1) & 3)) * 8;          // swizzled read slot
    const int vkk = w >> 1, vdg = (w & 1) * 4;

    f32x4 acco[8] = {};
    float den[4] = {0.f, 0.f, 0.f, 0.f};

    for (int kt = jt0; kt < jt1; ++kt) {
        const int jb = kt * 64;
        __syncthreads();
        #pragma unroll
        for (int rg = 0; rg < 4; ++rg)
            gload_lds16(&k[(size_t)(jb + rg * 16 + sr4) * KVD + kvh * HD + w * 32 + sc4],
                        &Ks4[w][rg * 16][0]);
        #pragma unroll
        for (int it = 0; it < 4; ++it)
            gload_lds16(&vT[(size_t)(kvh * HD + (vdg + it) * 16 + sr4) * S_LEN + jb + vkk * 32 + sc4],
                        &Vt4[vkk][(vdg + it) * 16][0]);
        __syncthreads();

        f32x4 accs[4] = {};
        #pragma unroll
        for (int t = 0; t < 4; ++t)
            #pragma unroll
            for (int kc = 0; kc < 4; ++kc) {
                bf16x8 bfr = *(const bf16x8*)&Ks4[kc][t * 16 + l16][rsl];
                accs[t] = __builtin_amdgcn_mfma_f32_16x16x32_bf16(qf[kc], bfr, accs[t], 0, 0, 0);
            }

        const float Gt = G[kvh * S_LEN + jb];
        float sr[4];
        #pragma unroll
        for (int r = 0; r < 4; ++r) sr[r] = SCALE2 * __expf(Gq[r] - Gt);
        #pragma unroll
        for (int t = 0; t < 4; ++t) {
            int j = jb + t * 16 + l16;
            float colF = __expf(fminf(Gt - G[kvh * S_LEN + j], 85.f));
            #pragma unroll
            for (int r = 0; r < 4; ++r) {
                float d0 = accs[t][r];
                float sc = (j <= irow + r) ? d0 * d0 * sr[r] * colF : 0.f;
                den[r] += sc;
                Sb[w][quad * 4 + r][t * 16 + l16] = (bf16)sc;
            }
        }
        // no barrier: Sb[w] is wave-private

        #pragma unroll
        for (int kk = 0; kk < 2; ++kk) {
            bf16x8 af = *(const bf16x8*)&Sb[w][l16][kk * 32 + quad * 8];
            #pragma unroll
            for (int dt = 0; dt < 8; ++dt) {
                bf16x8 bfr = *(const bf16x8*)&Vt4[kk][dt * 16 + l16][rsl];
                acco[dt] = __builtin_amdgcn_mfma_f32_16x16x32_bf16(af, bfr, acco[dt], 0, 0, 0);
            }
        }
    }

    #pragma unroll
    for (int r = 0; r < 4; ++r) {
        #pragma unroll
        for (int off = 1; off < 16; off <<= 1) den[r] += __shfl_xor(den[r], off);
    }

    if (nc == 1) {
        float dinv[4];
        #pragma unroll
        for (int r = 0; r < 4; ++r) dinv[r] = 1.f / fmaxf(den[r], 1.f);
        #pragma unroll
        for (int dt = 0; dt < 8; ++dt)
            #pragma unroll
            for (int r = 0; r < 4; ++r)
                out[(size_t)(irow + r) * HID + h * HD + dt * 16 + l16] =
                    (bf16)(acco[dt][r] * dinv[r]);
    } else {
        const int slot = h * NCH + 4 * gg * (gg + 1) + (qt & 7) * (gg + 1) + cch;
        float* po = &pO[(size_t)slot * 8192];
        const int lr = w * 16 + quad * 4;
        #pragma unroll
        for (int dt = 0; dt < 8; ++dt)
            #pragma unroll
            for (int r = 0; r < 4; ++r)
                po[(lr + r) * 128 + dt * 16 + l16] = acco[dt][r];
        if (l16 == 0) {
            #pragma unroll
            for (int r = 0; r < 4; ++r) pden[slot * 64 + lr + r] = den[r];
        }
    }
}

// Combine partial chunks for qt >= 8. Grid: 16 heads x 24 qts.
__global__ __launch_bounds__(256) void attn_reduce_kernel(const float* __restrict__ pO,
                                                          const float* __restrict__ pden,
                                                          bf16* __restrict__ out)
{
    const int p = blockIdx.x;
    const int h = p / 24, qt = 8 + p % 24;
    const int gg = qt >> 3, nc = gg + 1;
    const int base = h * NCH + 4 * gg * (gg + 1) + (qt & 7) * (gg + 1);
    const int qb = qt * 64;
    const int tid = threadIdx.x;

    __shared__ float sden[64];
    if (tid < 64) {
        float s = 0.f;
        for (int c = 0; c < nc; ++c) s += pden[(base + c) * 64 + tid];
        sden[tid] = 1.f / fmaxf(s, 1.f);
    }
    __syncthreads();

    #pragma unroll
    for (int i = 0; i < 8; ++i) {
        int e = i * 1024 + tid * 4;
        float4 s = make_float4(0.f, 0.f, 0.f, 0.f);
        for (int c = 0; c < nc; ++c) {
            float4 v = *(const float4*)&pO[(size_t)(base + c) * 8192 + e];
            s.x += v.x; s.y += v.y; s.z += v.z; s.w += v.w;
        }
        int lr = e >> 7, col = e & 127;
        float di = sden[lr];
        bf16* o = &out[(size_t)(qb + lr) * HID + h * HD + col];
        o[0] = (bf16)(s.x * di); o[1] = (bf16)(s.y * di);
        o[2] = (bf16)(s.z * di); o[3] = (bf16)(s.w * di);
    }
}

// ---------------------------------------------------------------------------
extern "C" void kernel_launch(void* const* d_in, const int* in_sizes, int n_in,
                              void* d_out, int out_size, void* d_ws, size_t ws_size,
                              hipStream_t stream)
{
    const float* hs   = (const float*)d_in[0];
    const float* cosb = (const float*)d_in[1];
    const float* sinb = (const float*)d_in[2];
    const float* Wq   = (const float*)d_in[3];
    const float* Wk   = (const float*)d_in[4];
    const float* Wv   = (const float*)d_in[5];
    const float* Wg   = (const float*)d_in[6];
    const float* Wo   = (const float*)d_in[7];
    float* out = (float*)d_out;

    char* p = (char*)d_ws;
    bf16*  qbuf  = (bf16*)p;  p += (size_t)S_LEN * HID * 2;    // 8 MB
    bf16*  kbuf  = (bf16*)p;  p += (size_t)S_LEN * KVD * 2;    // 2 MB
    bf16*  vT    = (bf16*)p;  p += (size_t)S_LEN * KVD * 2;    // 2 MB ([KVD][S])
    bf16*  abuf  = (bf16*)p;  p += (size_t)S_LEN * HID * 2;    // 8 MB
    bf16*  hsb   = (bf16*)p;  p += (size_t)S_LEN * HID * 2;    // 8 MB
    bf16*  WcatT = (bf16*)p;  p += (size_t)NQKV * HID * 2;     // 12 MB
    bf16*  WoT   = (bf16*)p;  p += (size_t)HID * HID * 2;      // 8 MB
    float* graw  = (float*)p; p += (size_t)NKV * S_LEN * 4;
    float* G     = (float*)p; p += (size_t)NKV * S_LEN * 4;
    float* pO    = (float*)p; p += (size_t)NH * NCH * 8192 * 4; // 41.9 MB
    float* pden  = (float*)p; p += (size_t)NH * NCH * 64 * 4;   // 0.33 MB

    // qkv split-K slice buffers, phase-disjoint aliases (proven):
    float* qsl = pO;                                  // [2][S*HID]
    float* ksl = pO + (size_t)8 * 1024 * 1024;        // [2][S*KVD]
    float* vsl = (float*)abuf;                        // [2][KVD*S]

    // 1: fused pre-pass (cvt + fused gproj + transposes + zero-out)
    prep_kernel<<<6656, 256, 0, stream>>>(hs, Wq, Wk, Wv, Wo, Wg,
                                          hsb, WcatT, WoT, graw, out);
    // 2: fused QKV projection, BK=32 swizzled core, split-K=2, plain stores
    gemm_qkv_kernel<<<dim3(384, 1, 2), 256, 0, stream>>>(hsb, WcatT, qsl, ksl, vsl, S_LEN, HID);
    // 3: merged RoPE (vectorized slice-sum f32 -> bf16) + v cvt + gate cumsum
    rope_kernel<<<RQB2 + RKB2 + RVB + NKV, 256, 0, stream>>>(qsl, ksl, vsl, qbuf, kbuf, vT,
                                                             cosb, sinb, graw, G);
    // 4: j-split attention (LDS-staged, QBLK=64, swizzled K/V, long-first)
    attn_kernel<<<dim3(NCH, NH), 256, 0, stream>>>(qbuf, kbuf, vT, G, abuf, pO, pden);
    // 5: combine
    attn_reduce_kernel<<<NH * 24, 256, 0, stream>>>(pO, pden, abuf);
    // 6: output projection (BK=64 swizzled core, split-K=2, atomics)
    gemm_wo_kernel<<<dim3(256, 1, 2), 256, 0, stream>>>(abuf, WoT, out, S_LEN, HID, HID);
}

// Round 26
// 270.808 us; speedup vs baseline: 1.0151x; 1.0151x over previous
//
#include <hip/hip_runtime.h>
#include <hip/hip_bf16.h>

#define S_LEN 2048
#define HID   2048
#define NH    16
#define NKV   4
#define HD    128
#define KVD   512            // NKV*HD
#define NQKV  3072           // HID + KVD + KVD
#define SCALE2 0.0078125f    // (D^-0.5)^2 = 1/128
#define NCH   80             // j-chunk slots per head: sum_{qt} ceil((qt+1)/8)

typedef __bf16 bf16;
typedef __attribute__((ext_vector_type(8))) __bf16 bf16x8;
typedef __attribute__((ext_vector_type(4))) __bf16 bf16x4;
typedef __attribute__((ext_vector_type(4))) float f32x4;

// async global->LDS, 16B per lane; LDS dest is wave-uniform base + lane*16
__device__ __forceinline__ void gload_lds16(const bf16* g, bf16* l) {
    __builtin_amdgcn_global_load_lds((const __attribute__((address_space(1))) void*)g,
                                     (__attribute__((address_space(3))) void*)l, 16, 0, 0);
}

// ---------------------------------------------------------------------------
// Within-64B both-sides XOR swizzle (rule #21):
//   LDS rows are 64 B = four 16 B slots. Physical slot sp of row r holds
//   logical slot sp ^ ((r>>1)&3). Staged via linear gload_lds dest +
//   permuted GLOBAL source col ((lane&3)^((lane>>3)&3))*8 (stays inside the
//   same 64-B run per 4-lane group => FETCH unchanged). Reads XOR the slot
//   with ((l16>>1)&3). Turns the 8-way b128 fragment-read conflict into
//   2-way (= free, m136). Round-11 verified: qkv conflicts 3.15M -> 0,
//   FETCH flat, refcheck pass.
// ---------------------------------------------------------------------------

// ---------------------------------------------------------------------------
// Fused pre-pass. Region-decoded grid:
//   [0,2048)    : hs f32 -> hsb bf16  + FUSED gate projection (row b)
//   [2048,3072) : Wq transpose-cvt -> WcatT[0]
//   [3072,3328) : Wk -> WcatT[2048*HID]
//   [3328,3584) : Wv -> WcatT[2560*HID]
//   [3584,4608) : Wo -> WoT
//   [4608,6656) : zero d_out (for wo atomics)
// ---------------------------------------------------------------------------
__device__ __forceinline__ void transpose_tile(const float* __restrict__ W,
                                               bf16* __restrict__ Wt,
                                               int K, int N, int bx, int by,
                                               int t, float (*Ts)[65])
{
    const int kb = bx * 64, nb = by * 64;
    const int tr = t >> 6, tc = t & 63;
    #pragma unroll
    for (int p = 0; p < 16; ++p) {
        int k = p * 4 + tr;
        Ts[k][tc] = W[(size_t)(kb + k) * N + nb + tc];
    }
    __syncthreads();
    const int nr = t >> 3, kc = t & 7;
    #pragma unroll
    for (int p = 0; p < 2; ++p) {
        int n = p * 32 + nr;
        bf16x8 o;
        #pragma unroll
        for (int x = 0; x < 8; ++x) o[x] = (bf16)Ts[kc * 8 + x][n];
        *(bf16x8*)&Wt[(size_t)(nb + n) * K + kb + kc * 8] = o;
    }
}

__global__ __launch_bounds__(256) void prep_kernel(const float* __restrict__ hs,
                                                   const float* __restrict__ Wq,
                                                   const float* __restrict__ Wk,
                                                   const float* __restrict__ Wv,
                                                   const float* __restrict__ Wo,
                                                   const float* __restrict__ Wg,
                                                   bf16* __restrict__ hsb,
                                                   bf16* __restrict__ WcatT,
                                                   bf16* __restrict__ WoT,
                                                   float* __restrict__ graw,
                                                   float* __restrict__ outz)
{
    __shared__ float Ts[64][65];
    __shared__ float red[4][4];
    const int b = blockIdx.x, tid = threadIdx.x;

    if (b < 2048) {                                   // cvt hs -> hsb + gproj
        int i = (b * 256 + tid) * 8;
        const float4* qp = (const float4*)&hs[i];
        float4 a = qp[0], c = qp[1];
        bf16x8 r;
        r[0]=(bf16)a.x; r[1]=(bf16)a.y; r[2]=(bf16)a.z; r[3]=(bf16)a.w;
        r[4]=(bf16)c.x; r[5]=(bf16)c.y; r[6]=(bf16)c.z; r[7]=(bf16)c.w;
        *(bf16x8*)&hsb[i] = r;

        const float4* wgp = (const float4*)&Wg[tid * 32];   // 8 float4 rows
        float h[8] = {a.x, a.y, a.z, a.w, c.x, c.y, c.z, c.w};
        float a0 = 0.f, a1 = 0.f, a2 = 0.f, a3 = 0.f;
        #pragma unroll
        for (int x = 0; x < 8; ++x) {
            float4 w = wgp[x];
            a0 += h[x] * w.x; a1 += h[x] * w.y;
            a2 += h[x] * w.z; a3 += h[x] * w.w;
        }
        #pragma unroll
        for (int off = 32; off >= 1; off >>= 1) {
            a0 += __shfl_xor(a0, off); a1 += __shfl_xor(a1, off);
            a2 += __shfl_xor(a2, off); a3 += __shfl_xor(a3, off);
        }
        const int w4 = tid >> 6;
        if ((tid & 63) == 0) {
            red[w4][0] = a0; red[w4][1] = a1; red[w4][2] = a2; red[w4][3] = a3;
        }
        __syncthreads();
        if (tid == 0) {
            #pragma unroll
            for (int cc = 0; cc < 4; ++cc) {
                float x = red[0][cc] + red[1][cc] + red[2][cc] + red[3][cc];
                graw[cc * S_LEN + b] = fminf(x, 0.f) - log1pf(expf(-fabsf(x)));
            }
        }
    } else if (b < 3072) {
        int lb = b - 2048;
        transpose_tile(Wq, WcatT, HID, HID, lb >> 5, lb & 31, tid, Ts);
    } else if (b < 3328) {
        int lb = b - 3072;
        transpose_tile(Wk, WcatT + (size_t)2048 * HID, HID, KVD, lb >> 3, lb & 7, tid, Ts);
    } else if (b < 3584) {
        int lb = b - 3328;
        transpose_tile(Wv, WcatT + (size_t)2560 * HID, HID, KVD, lb >> 3, lb & 7, tid, Ts);
    } else if (b < 4608) {
        int lb = b - 3584;
        transpose_tile(Wo, WoT, HID, HID, lb >> 5, lb & 31, tid, Ts);
    } else {                                          // zero d_out
        int i = ((b - 4608) * 256 + tid) * 8;
        float4 z = make_float4(0.f, 0.f, 0.f, 0.f);
        *(float4*)&outz[i] = z;
        *(float4*)&outz[i + 4] = z;
    }
}

// ---------------------------------------------------------------------------
// m97-style GEMM core loop: 128x128 tile, BK=32, 4 waves, 4x4 MFMA grid.
// Within-64B both-sides XOR swizzle applied (8-way -> 2-way on frag reads).
// Used by gemm_qkv. (BK=64 falsified twice for this shape: r4 & r12.)
// ---------------------------------------------------------------------------
__device__ __forceinline__ void gemm128_core(const bf16* __restrict__ A,
                                             const bf16* __restrict__ Bt,
                                             int K, int k0, int k1, int mb, int nb,
                                             bf16 (*As)[32], bf16 (*Bs)[32],
                                             f32x4 (*acc)[4],
                                             int w, int l16, int quad, int lane)
{
    const int m0 = (w & 1) * 64, n0 = (w >> 1) * 64;
    const int srow = lane >> 2;
    const int scol = ((lane & 3) ^ ((lane >> 3) & 3)) * 8;   // pre-swizzled src
    const int rsl  = (quad ^ ((l16 >> 1) & 3)) * 8;          // swizzled read slot

    for (int kt = k0; kt < k1; kt += 32) {
        __syncthreads();
        gload_lds16(&A [(size_t)(mb + w * 32 +      srow) * K + kt + scol], &As[w * 32     ][0]);
        gload_lds16(&A [(size_t)(mb + w * 32 + 16 + srow) * K + kt + scol], &As[w * 32 + 16][0]);
        gload_lds16(&Bt[(size_t)(nb + w * 32 +      srow) * K + kt + scol], &Bs[w * 32     ][0]);
        gload_lds16(&Bt[(size_t)(nb + w * 32 + 16 + srow) * K + kt + scol], &Bs[w * 32 + 16][0]);
        __syncthreads();

        bf16x8 af[4], bfr[4];
        #pragma unroll
        for (int t = 0; t < 4; ++t) af[t]  = *(const bf16x8*)&As[m0 + t * 16 + l16][rsl];
        #pragma unroll
        for (int u = 0; u < 4; ++u) bfr[u] = *(const bf16x8*)&Bs[n0 + u * 16 + l16][rsl];
        #pragma unroll
        for (int t = 0; t < 4; ++t)
            #pragma unroll
            for (int u = 0; u < 4; ++u)
                acc[t][u] = __builtin_amdgcn_mfma_f32_16x16x32_bf16(af[t], bfr[u], acc[t][u], 0, 0, 0);
    }
}

// ---------------------------------------------------------------------------
// 128x128 GEMM core, BK=64, single 32 KB LDS buffer, both-sides XOR swizzle
// (round-4-verified correct; proven faster for the wo shape).
// ---------------------------------------------------------------------------
__device__ __forceinline__ void gemm128_bk64(const bf16* __restrict__ A,
                                             const bf16* __restrict__ Bt,
                                             int K, int k0, int k1, int mb, int nb,
                                             bf16 (*As)[64], bf16 (*Bs)[64],
                                             f32x4 (*acc)[4],
                                             int w, int l16, int quad, int lane)
{
    const int m0 = (w & 1) * 64, n0 = (w >> 1) * 64;
    const int srow8 = lane >> 3;                    // 0..7
    const int scol8 = ((lane & 7) ^ srow8) * 8;     // pre-swizzled col (elems)
    const bf16* aP[4]; const bf16* bP[4];
    #pragma unroll
    for (int i = 0; i < 4; ++i) {
        aP[i] = &A [(size_t)(mb + w * 32 + i * 8 + srow8) * K + k0 + scol8];
        bP[i] = &Bt[(size_t)(nb + w * 32 + i * 8 + srow8) * K + k0 + scol8];
    }
    const int rsw = (l16 & 7) << 3;                 // read-side XOR (elems)

    const int nk = k1 - k0;
    for (int kt = 0; kt < nk; kt += 64) {
        __syncthreads();                            // prev-tile reads done
        #pragma unroll
        for (int i = 0; i < 4; ++i) {
            gload_lds16(aP[i] + kt, &As[w * 32 + i * 8][0]);
            gload_lds16(bP[i] + kt, &Bs[w * 32 + i * 8][0]);
        }
        __syncthreads();                            // loads landed (vmcnt drain)

        #pragma unroll
        for (int kk = 0; kk < 2; ++kk) {
            bf16x8 af[4], bfr[4];
            #pragma unroll
            for (int t = 0; t < 4; ++t)
                af[t]  = *(const bf16x8*)&As[m0 + t * 16 + l16][(kk * 32 + quad * 8) ^ rsw];
            #pragma unroll
            for (int u = 0; u < 4; ++u)
                bfr[u] = *(const bf16x8*)&Bs[n0 + u * 16 + l16][(kk * 32 + quad * 8) ^ rsw];
            #pragma unroll
            for (int t = 0; t < 4; ++t)
                #pragma unroll
                for (int u = 0; u < 4; ++u)
                    acc[t][u] = __builtin_amdgcn_mfma_f32_16x16x32_bf16(af[t], bfr[u], acc[t][u], 0, 0, 0);
        }
    }
}

// Fused QKV projection, split-K=2, PLAIN f32 stores into per-z slice buffers.
// Grid: (384, 1, 2) flat; XCD-bijective swizzle (384 % 8 == 0).
__global__ __launch_bounds__(256) void gemm_qkv_kernel(const bf16* __restrict__ A,
                                                       const bf16* __restrict__ Wt,
                                                       float* __restrict__ qsl,   // [2][S*HID]
                                                       float* __restrict__ ksl,   // [2][S*KVD]
                                                       float* __restrict__ vsl,   // [2][KVD*S]
                                                       int M, int K)
{
    __shared__ __attribute__((aligned(16))) bf16 As[128][32];
    __shared__ __attribute__((aligned(16))) bf16 Bs[128][32];
    const int tid = threadIdx.x, w = tid >> 6, lane = tid & 63;
    const int l16 = lane & 15, quad = lane >> 4;

    const int bid = blockIdx.x;                  // 0..383
    const int lin = (bid & 7) * 48 + (bid >> 3); // XCD chunking (bijective)
    const int mb = (lin / 24) * 128, nb = (lin % 24) * 128;

    const int m0 = (w & 1) * 64, n0 = (w >> 1) * 64;
    const int z = blockIdx.z, kh = K >> 1, k0 = z * kh;

    float* qd = qsl + (size_t)z * S_LEN * HID;
    float* kd = ksl + (size_t)z * S_LEN * KVD;
    float* vd = vsl + (size_t)z * S_LEN * KVD;

    f32x4 acc[4][4] = {};
    gemm128_core(A, Wt, K, k0, k0 + kh, mb, nb, As, Bs, acc, w, l16, quad, lane);

    #pragma unroll
    for (int t = 0; t < 4; ++t)
        #pragma unroll
        for (int u = 0; u < 4; ++u)
            #pragma unroll
            for (int r = 0; r < 4; ++r) {
                int row = mb + m0 + t * 16 + quad * 4 + r;
                int col = nb + n0 + u * 16 + l16;
                float val = acc[t][u][r];
                if (nb < 2048)       qd[(size_t)row * HID + col] = val;
                else if (nb < 2560)  kd[(size_t)row * KVD + (col - 2048)] = val;
                else                 vd[(size_t)(col - 2560) * S_LEN + row] = val;
            }
}

// Wo GEMM, split-K=2, atomic f32 accumulate into pre-zeroed out.
// BK=64 swizzled core. Grid: (256, 1, 2) flat; XCD-bijective swizzle.
__global__ __launch_bounds__(256) void gemm_wo_kernel(const bf16* __restrict__ A,
                                                      const bf16* __restrict__ Bt,
                                                      float* __restrict__ C,
                                                      int M, int N, int K)
{
    __shared__ __attribute__((aligned(16))) bf16 As[128][64];
    __shared__ __attribute__((aligned(16))) bf16 Bs[128][64];
    const int tid = threadIdx.x, w = tid >> 6, lane = tid & 63;
    const int l16 = lane & 15, quad = lane >> 4;

    const int bid = blockIdx.x;                  // 0..255
    const int lin = (bid & 7) * 32 + (bid >> 3); // XCD chunking (bijective)
    const int mb = (lin >> 4) * 128, nb = (lin & 15) * 128;

    const int m0 = (w & 1) * 64, n0 = (w >> 1) * 64;
    const int kh = K >> 1, k0 = blockIdx.z * kh;

    f32x4 acc[4][4] = {};
    gemm128_bk64(A, Bt, K, k0, k0 + kh, mb, nb, As, Bs, acc, w, l16, quad, lane);

    #pragma unroll
    for (int t = 0; t < 4; ++t)
        #pragma unroll
        for (int u = 0; u < 4; ++u)
            #pragma unroll
            for (int r = 0; r < 4; ++r) {
                int row = mb + m0 + t * 16 + quad * 4 + r;
                int col = nb + n0 + u * 16 + l16;
                unsafeAtomicAdd(&C[(size_t)row * N + col], acc[t][u][r]);
            }
}

// ---------------------------------------------------------------------------
// Merged RoPE, VECTORIZED (round-3 proven).
// ---------------------------------------------------------------------------
#define RQB2 2048   // S*NH*64 pairs / 4 per thread / 256
#define RKB2 512    // S*NKV*64 pairs / 4 per thread / 256
#define RVB  512    // S*KVD / 8 / 256
__global__ __launch_bounds__(256) void rope_kernel(const float* __restrict__ qsl,
                                                   const float* __restrict__ ksl,
                                                   const float* __restrict__ vsl,
                                                   bf16* __restrict__ qb,
                                                   bf16* __restrict__ kb,
                                                   bf16* __restrict__ vT,
                                                   const float* __restrict__ cosb,
                                                   const float* __restrict__ sinb,
                                                   const float* __restrict__ graw,
                                                   float* __restrict__ G)
{
    const int blk = blockIdx.x;
    if (blk < RQB2 + RKB2) {
        int idx;
        const float* src; size_t ssz; bf16* dst; int s, rem, stride;
        if (blk < RQB2) {
            idx = (blk * 256 + threadIdx.x) * 4;           // pair index
            src = qsl; ssz = (size_t)S_LEN * HID; dst = qb; stride = HID;
            s = idx / (NH * 64); rem = idx % (NH * 64);
        } else {
            idx = ((blk - RQB2) * 256 + threadIdx.x) * 4;
            src = ksl; ssz = (size_t)S_LEN * KVD; dst = kb; stride = KVD;
            s = idx / (NKV * 64); rem = idx % (NKV * 64);
        }
        int h = rem >> 6, d = rem & 63;                    // d multiple of 4
        size_t base = (size_t)s * stride + h * 128 + d;
        float4 lo0 = *(const float4*)&src[base];
        float4 lo1 = *(const float4*)&src[ssz + base];
        float4 hi0 = *(const float4*)&src[base + 64];
        float4 hi1 = *(const float4*)&src[ssz + base + 64];
        float4 cl  = *(const float4*)&cosb[s * 128 + d];
        float4 ch  = *(const float4*)&cosb[s * 128 + d + 64];
        float4 sl  = *(const float4*)&sinb[s * 128 + d];
        float4 sh  = *(const float4*)&sinb[s * 128 + d + 64];
        float x0[4] = {lo0.x + lo1.x, lo0.y + lo1.y, lo0.z + lo1.z, lo0.w + lo1.w};
        float x1[4] = {hi0.x + hi1.x, hi0.y + hi1.y, hi0.z + hi1.z, hi0.w + hi1.w};
        float clo[4] = {cl.x, cl.y, cl.z, cl.w}, chi[4] = {ch.x, ch.y, ch.z, ch.w};
        float slo[4] = {sl.x, sl.y, sl.z, sl.w}, shi[4] = {sh.x, sh.y, sh.z, sh.w};
        bf16x4 olo, ohi;
        #pragma unroll
        for (int x = 0; x < 4; ++x) {
            olo[x] = (bf16)(x0[x] * clo[x] - x1[x] * slo[x]);
            ohi[x] = (bf16)(x1[x] * chi[x] + x0[x] * shi[x]);
        }
        *(bf16x4*)&dst[base]      = olo;
        *(bf16x4*)&dst[base + 64] = ohi;
    } else if (blk < RQB2 + RKB2 + RVB) {
        int i = ((blk - RQB2 - RKB2) * 256 + threadIdx.x) * 8;
        const size_t ssz = (size_t)S_LEN * KVD;
        float4 u0 = *(const float4*)&vsl[i],       u1 = *(const float4*)&vsl[i + 4];
        float4 v0 = *(const float4*)&vsl[ssz + i], v1 = *(const float4*)&vsl[ssz + i + 4];
        bf16x8 r;
        r[0] = (bf16)(u0.x + v0.x); r[1] = (bf16)(u0.y + v0.y);
        r[2] = (bf16)(u0.z + v0.z); r[3] = (bf16)(u0.w + v0.w);
        r[4] = (bf16)(u1.x + v1.x); r[5] = (bf16)(u1.y + v1.y);
        r[6] = (bf16)(u1.z + v1.z); r[7] = (bf16)(u1.w + v1.w);
        *(bf16x8*)&vT[i] = r;
    } else {                               // cumsum, one block per kv head
        const int c = blk - (RQB2 + RKB2 + RVB);
        const int t = threadIdx.x;
        __shared__ float sums[256];
        float loc[8];
        float run = 0.f;
        #pragma unroll
        for (int i = 0; i < 8; ++i) { run += graw[c * S_LEN + t * 8 + i]; loc[i] = run; }
        sums[t] = run;
        __syncthreads();
        for (int off = 1; off < 256; off <<= 1) {
            float add = (t >= off) ? sums[t - off] : 0.f;
            __syncthreads();
            sums[t] += add;
            __syncthreads();
        }
        float offset = sums[t] - run;
        #pragma unroll
        for (int i = 0; i < 8; ++i) G[c * S_LEN + t * 8 + i] = offset + loc[i];
    }
}

// ---------------------------------------------------------------------------
// Causal decay attention, j-split, LDS-staged QBLK=64 (round-11 state:
// within-64B both-sides XOR swizzle on K/V staging + fragment reads).
// Block index REVERSED so the longest chunks (8 j-tiles, large qt) dispatch
// first and short blocks backfill the tail (load-balance; work-neutral).
// ---------------------------------------------------------------------------
__global__ __launch_bounds__(256) void attn_kernel(const bf16* __restrict__ q,
                                                   const bf16* __restrict__ k,
                                                   const bf16* __restrict__ vT,
                                                   const float* __restrict__ G,
                                                   bf16* __restrict__ out,
                                                   float* __restrict__ pO,
                                                   float* __restrict__ pden)
{
    int rem = (NCH - 1) - blockIdx.x, qt = 0, cch = 0;   // reversed: long first
    #pragma unroll
    for (int g = 0; g < 4; ++g) {
        int sz = 8 * (g + 1);
        if (rem < sz) { qt = g * 8 + rem / (g + 1); cch = rem % (g + 1); break; }
        rem -= sz;
    }
    const int gg = qt >> 3, nc = gg + 1;
    const int jt0 = cch * 8, jt1 = min(qt + 1, jt0 + 8);

    const int h = blockIdx.y, kvh = h >> 2;
    const int qb = qt * 64;
    const int tid = threadIdx.x, w = tid >> 6, lane = tid & 63;
    const int l16 = lane & 15, quad = lane >> 4;

    __shared__ __attribute__((aligned(16))) bf16 Ks4[4][64][32];
    __shared__ __attribute__((aligned(16))) bf16 Vt4[2][128][32];
    __shared__ __attribute__((aligned(16))) bf16 Sb[4][16][68];

    bf16x8 qf[4];
    const int qrow = qb + w * 16 + l16;
    #pragma unroll
    for (int kc = 0; kc < 4; ++kc)
        qf[kc] = *(const bf16x8*)&q[(size_t)qrow * HID + h * HD + kc * 32 + quad * 8];

    const int irow = qb + w * 16 + quad * 4;
    float Gq[4];
    #pragma unroll
    for (int r = 0; r < 4; ++r) Gq[r] = G[kvh * S_LEN + irow + r];

    const int sr4 = lane >> 2;
    const int sc4 = ((lane & 3) ^ ((lane >> 3) & 3)) * 8;   // pre-swizzled src
    const int rsl = (quad ^ ((l16 >> 1) & 3)) * 8;          // swizzled read slot
    const int vkk = w >> 1, vdg = (w & 1) * 4;

    f32x4 acco[8] = {};
    float den[4] = {0.f, 0.f, 0.f, 0.f};

    for (int kt = jt0; kt < jt1; ++kt) {
        const int jb = kt * 64;
        __syncthreads();
        #pragma unroll
        for (int rg = 0; rg < 4; ++rg)
            gload_lds16(&k[(size_t)(jb + rg * 16 + sr4) * KVD + kvh * HD + w * 32 + sc4],
                        &Ks4[w][rg * 16][0]);
        #pragma unroll
        for (int it = 0; it < 4; ++it)
            gload_lds16(&vT[(size_t)(kvh * HD + (vdg + it) * 16 + sr4) * S_LEN + jb + vkk * 32 + sc4],
                        &Vt4[vkk][(vdg + it) * 16][0]);
        __syncthreads();

        f32x4 accs[4] = {};
        #pragma unroll
        for (int t = 0; t < 4; ++t)
            #pragma unroll
            for (int kc = 0; kc < 4; ++kc) {
                bf16x8 bfr = *(const bf16x8*)&Ks4[kc][t * 16 + l16][rsl];
                accs[t] = __builtin_amdgcn_mfma_f32_16x16x32_bf16(qf[kc], bfr, accs[t], 0, 0, 0);
            }

        const float Gt = G[kvh * S_LEN + jb];
        float sr[4];
        #pragma unroll
        for (int r = 0; r < 4; ++r) sr[r] = SCALE2 * __expf(Gq[r] - Gt);
        #pragma unroll
        for (int t = 0; t < 4; ++t) {
            int j = jb + t * 16 + l16;
            float colF = __expf(fminf(Gt - G[kvh * S_LEN + j], 85.f));
            #pragma unroll
            for (int r = 0; r < 4; ++r) {
                float d0 = accs[t][r];
                float sc = (j <= irow + r) ? d0 * d0 * sr[r] * colF : 0.f;
                den[r] += sc;
                Sb[w][quad * 4 + r][t * 16 + l16] = (bf16)sc;
            }
        }
        // no barrier: Sb[w] is wave-private

        #pragma unroll
        for (int kk = 0; kk < 2; ++kk) {
            bf16x8 af = *(const bf16x8*)&Sb[w][l16][kk * 32 + quad * 8];
            #pragma unroll
            for (int dt = 0; dt < 8; ++dt) {
                bf16x8 bfr = *(const bf16x8*)&Vt4[kk][dt * 16 + l16][rsl];
                acco[dt] = __builtin_amdgcn_mfma_f32_16x16x32_bf16(af, bfr, acco[dt], 0, 0, 0);
            }
        }
    }

    #pragma unroll
    for (int r = 0; r < 4; ++r) {
        #pragma unroll
        for (int off = 1; off < 16; off <<= 1) den[r] += __shfl_xor(den[r], off);
    }

    if (nc == 1) {
        float dinv[4];
        #pragma unroll
        for (int r = 0; r < 4; ++r) dinv[r] = 1.f / fmaxf(den[r], 1.f);
        #pragma unroll
        for (int dt = 0; dt < 8; ++dt)
            #pragma unroll
            for (int r = 0; r < 4; ++r)
                out[(size_t)(irow + r) * HID + h * HD + dt * 16 + l16] =
                    (bf16)(acco[dt][r] * dinv[r]);
    } else {
        const int slot = h * NCH + 4 * gg * (gg + 1) + (qt & 7) * (gg + 1) + cch;
        float* po = &pO[(size_t)slot * 8192];
        const int lr = w * 16 + quad * 4;
        #pragma unroll
        for (int dt = 0; dt < 8; ++dt)
            #pragma unroll
            for (int r = 0; r < 4; ++r)
                po[(lr + r) * 128 + dt * 16 + l16] = acco[dt][r];
        if (l16 == 0) {
            #pragma unroll
            for (int r = 0; r < 4; ++r) pden[slot * 64 + lr + r] = den[r];
        }
    }
}

// Combine partial chunks for qt >= 8. Grid: 16 heads x 24 qts.
__global__ __launch_bounds__(256) void attn_reduce_kernel(const float* __restrict__ pO,
                                                          const float* __restrict__ pden,
                                                          bf16* __restrict__ out)
{
    const int p = blockIdx.x;
    const int h = p / 24, qt = 8 + p % 24;
    const int gg = qt >> 3, nc = gg + 1;
    const int base = h * NCH + 4 * gg * (gg + 1) + (qt & 7) * (gg + 1);
    const int qb = qt * 64;
    const int tid = threadIdx.x;

    __shared__ float sden[64];
    if (tid < 64) {
        float s = 0.f;
        for (int c = 0; c < nc; ++c) s += pden[(base + c) * 64 + tid];
        sden[tid] = 1.f / fmaxf(s, 1.f);
    }
    __syncthreads();

    #pragma unroll
    for (int i = 0; i < 8; ++i) {
        int e = i * 1024 + tid * 4;
        float4 s = make_float4(0.f, 0.f, 0.f, 0.f);
        for (int c = 0; c < nc; ++c) {
            float4 v = *(const float4*)&pO[(size_t)(base + c) * 8192 + e];
            s.x += v.x; s.y += v.y; s.z += v.z; s.w += v.w;
        }
        int lr = e >> 7, col = e & 127;
        float di = sden[lr];
        bf16* o = &out[(size_t)(qb + lr) * HID + h * HD + col];
        o[0] = (bf16)(s.x * di); o[1] = (bf16)(s.y * di);
        o[2] = (bf16)(s.z * di); o[3] = (bf16)(s.w * di);
    }
}

// ---------------------------------------------------------------------------
extern "C" void kernel_launch(void* const* d_in, const int* in_sizes, int n_in,
                              void* d_out, int out_size, void* d_ws, size_t ws_size,
                              hipStream_t stream)
{
    const float* hs   = (const float*)d_in[0];
    const float* cosb = (const float*)d_in[1];
    const float* sinb = (const float*)d_in[2];
    const float* Wq   = (const float*)d_in[3];
    const float* Wk   = (const float*)d_in[4];
    const float* Wv   = (const float*)d_in[5];
    const float* Wg   = (const float*)d_in[6];
    const float* Wo   = (const float*)d_in[7];
    float* out = (float*)d_out;

    char* p = (char*)d_ws;
    bf16*  qbuf  = (bf16*)p;  p += (size_t)S_LEN * HID * 2;    // 8 MB
    bf16*  kbuf  = (bf16*)p;  p += (size_t)S_LEN * KVD * 2;    // 2 MB
    bf16*  vT    = (bf16*)p;  p += (size_t)S_LEN * KVD * 2;    // 2 MB ([KVD][S])
    bf16*  abuf  = (bf16*)p;  p += (size_t)S_LEN * HID * 2;    // 8 MB
    bf16*  hsb   = (bf16*)p;  p += (size_t)S_LEN * HID * 2;    // 8 MB
    bf16*  WcatT = (bf16*)p;  p += (size_t)NQKV * HID * 2;     // 12 MB
    bf16*  WoT   = (bf16*)p;  p += (size_t)HID * HID * 2;      // 8 MB
    float* graw  = (float*)p; p += (size_t)NKV * S_LEN * 4;
    float* G     = (float*)p; p += (size_t)NKV * S_LEN * 4;
    float* pO    = (float*)p; p += (size_t)NH * NCH * 8192 * 4; // 41.9 MB
    float* pden  = (float*)p; p += (size_t)NH * NCH * 64 * 4;   // 0.33 MB

    // qkv split-K slice buffers, phase-disjoint aliases (proven):
    float* qsl = pO;                                  // [2][S*HID]
    float* ksl = pO + (size_t)8 * 1024 * 1024;        // [2][S*KVD]
    float* vsl = (float*)abuf;                        // [2][KVD*S]

    // 1: fused pre-pass (cvt + fused gproj + transposes + zero-out)
    prep_kernel<<<6656, 256, 0, stream>>>(hs, Wq, Wk, Wv, Wo, Wg,
                                          hsb, WcatT, WoT, graw, out);
    // 2: fused QKV projection, BK=32 swizzled core, split-K=2, plain stores
    gemm_qkv_kernel<<<dim3(384, 1, 2), 256, 0, stream>>>(hsb, WcatT, qsl, ksl, vsl, S_LEN, HID);
    // 3: merged RoPE (vectorized slice-sum f32 -> bf16) + v cvt + gate cumsum
    rope_kernel<<<RQB2 + RKB2 + RVB + NKV, 256, 0, stream>>>(qsl, ksl, vsl, qbuf, kbuf, vT,
                                                             cosb, sinb, graw, G);
    // 4: j-split attention (LDS-staged, QBLK=64, swizzled K/V, long-first)
    attn_kernel<<<dim3(NCH, NH), 256, 0, stream>>>(qbuf, kbuf, vT, G, abuf, pO, pden);
    // 5: combine
    attn_reduce_kernel<<<NH * 24, 256, 0, stream>>>(pO, pden, abuf);
    // 6: output projection (BK=64 swizzled core, split-K=2, atomics)
    gemm_wo_kernel<<<dim3(256, 1, 2), 256, 0, stream>>>(abuf, WoT, out, S_LEN, HID, HID);
}